// Round 2
// baseline (358.951 us; speedup 1.0000x reference)
//
#include <hip/hip_runtime.h>
#include <math.h>

#define TILE_W 32
#define TILE_H 16
#define HALO 5
#define IH   26      // TILE_H + 2*HALO
#define LDSW 44      // padded input-tile row stride (float4-aligned)
#define HBW  36      // padded hb row stride (32 -> 36 floats, float4-aligned)

__global__ void zero_kernel(float* ws) { ws[0] = 0.0f; }

__global__ void finalize_kernel(const float* ws, float* out, float inv_n) {
    out[0] = 1.0f - ws[0] * inv_n;
}

// Reduce per-block partials -> final loss. One block, 1024 threads.
__global__ void reduce_kernel(const float* __restrict__ ws, float* __restrict__ out,
                              int n, float inv_n) {
    __shared__ float s[16];
    float a = 0.0f;
    for (int i = threadIdx.x; i < n; i += 1024) a += ws[i];
    #pragma unroll
    for (int off = 32; off > 0; off >>= 1) a += __shfl_down(a, off, 64);
    if ((threadIdx.x & 63) == 0) s[threadIdx.x >> 6] = a;
    __syncthreads();
    if (threadIdx.x == 0) {
        float t = 0.0f;
        #pragma unroll
        for (int w = 0; w < 16; ++w) t += s[w];
        out[0] = 1.0f - t * inv_n;
    }
}

// block = 256 threads, tile = 32x16 output pixels, loop over 3 channels.
// LDS = 27.9 KB -> 5 blocks/CU (vs 45 KB / 3 blocks in R1). 5 waves/EU bound.
__global__ __launch_bounds__(256, 5) void ssim_kernel(
    const float* __restrict__ img1, const float* __restrict__ img2,
    const float* __restrict__ window, float* __restrict__ ws,
    int H, int W, int use_partials)
{
    __shared__ float sx[IH][LDSW];
    __shared__ float sy[IH][LDSW];
    __shared__ float hb[5][IH][HBW];
    __shared__ float wsum[4];

    const int tid = threadIdx.x;
    const int x0  = blockIdx.x * TILE_W;
    const int y0  = blockIdx.y * TILE_H;

    // Recover separable 1D Gaussian: g[j] = w2d[5][j] / sqrt(w2d[5][5])
    float gr[11];
    {
        float inv = 1.0f / sqrtf(window[60]);
        #pragma unroll
        for (int t = 0; t < 11; ++t) gr[t] = window[55 + t] * inv;
    }

    // interior: every load of this block is in-bounds (gx in [x0-5, x0+38],
    // gy in [y0-5, y0+20])
    const bool interior = (x0 >= HALO) && (x0 + 39 <= W) &&
                          (y0 >= HALO) && (y0 + 21 <= H);

    float acc = 0.0f;

    for (int c = 0; c < 3; ++c) {
        __syncthreads();   // prev-iter readers of hb / sx,sy done

        // ---------- Stage A: stage input tile (26 rows x 44 cols) ----------
        if (interior) {
            for (int item = tid; item < IH * 11; item += 256) {
                int r   = item / 11;
                int j4  = (item % 11) * 4;
                long base = ((long)(y0 + r - HALO) * W + (x0 + j4 - HALO)) * 3 + c;
                float vx[4], vy[4];
                #pragma unroll
                for (int k = 0; k < 4; ++k) {
                    vx[k] = img1[base + 3 * k];
                    vy[k] = img2[base + 3 * k];
                }
                *(float4*)&sx[r][j4] = make_float4(vx[0], vx[1], vx[2], vx[3]);
                *(float4*)&sy[r][j4] = make_float4(vy[0], vy[1], vy[2], vy[3]);
            }
        } else {
            for (int item = tid; item < IH * 11; item += 256) {
                int r   = item / 11;
                int j4  = (item % 11) * 4;
                int gh  = y0 + r - HALO;
                int gx0 = x0 + j4 - HALO;
                bool rowok = ((unsigned)gh < (unsigned)H);
                float vx[4], vy[4];
                #pragma unroll
                for (int k = 0; k < 4; ++k) {
                    int gx = gx0 + k;
                    bool ok = rowok && ((unsigned)gx < (unsigned)W);
                    long off = ((long)gh * W + gx) * 3 + c;
                    vx[k] = ok ? img1[off] : 0.0f;
                    vy[k] = ok ? img2[off] : 0.0f;
                }
                *(float4*)&sx[r][j4] = make_float4(vx[0], vx[1], vx[2], vx[3]);
                *(float4*)&sy[r][j4] = make_float4(vy[0], vy[1], vy[2], vy[3]);
            }
        }
        __syncthreads();

        // ---------- Stage B: horizontal conv (5 quantities), 4 cols/thread --
        // 26 rows x 8 col-groups = 208 items -> single pass, threads 208+ idle
        if (tid < IH * 8) {
            int r  = tid >> 3;
            int j4 = (tid & 7) * 4;
            float xv[16], yv[16];
            *(float4*)&xv[0]  = *(const float4*)&sx[r][j4];
            *(float4*)&xv[4]  = *(const float4*)&sx[r][j4 + 4];
            *(float4*)&xv[8]  = *(const float4*)&sx[r][j4 + 8];
            *(float4*)&xv[12] = *(const float4*)&sx[r][j4 + 12];
            *(float4*)&yv[0]  = *(const float4*)&sy[r][j4];
            *(float4*)&yv[4]  = *(const float4*)&sy[r][j4 + 4];
            *(float4*)&yv[8]  = *(const float4*)&sy[r][j4 + 8];
            *(float4*)&yv[12] = *(const float4*)&sy[r][j4 + 12];

            float xx[14], yy[14], xy[14];
            #pragma unroll
            for (int t = 0; t < 14; ++t) {
                xx[t] = xv[t] * xv[t];
                yy[t] = yv[t] * yv[t];
                xy[t] = xv[t] * yv[t];
            }
            float h0[4] = {0,0,0,0}, h1[4] = {0,0,0,0}, h2[4] = {0,0,0,0};
            float h3[4] = {0,0,0,0}, h4[4] = {0,0,0,0};
            #pragma unroll
            for (int jj = 0; jj < 4; ++jj) {
                #pragma unroll
                for (int t = 0; t < 11; ++t) {
                    float g = gr[t];
                    h0[jj] += g * xv[jj + t];
                    h1[jj] += g * yv[jj + t];
                    h2[jj] += g * xx[jj + t];
                    h3[jj] += g * yy[jj + t];
                    h4[jj] += g * xy[jj + t];
                }
            }
            *(float4*)&hb[0][r][j4] = make_float4(h0[0], h0[1], h0[2], h0[3]);
            *(float4*)&hb[1][r][j4] = make_float4(h1[0], h1[1], h1[2], h1[3]);
            *(float4*)&hb[2][r][j4] = make_float4(h2[0], h2[1], h2[2], h2[3]);
            *(float4*)&hb[3][r][j4] = make_float4(h3[0], h3[1], h3[2], h3[3]);
            *(float4*)&hb[4][r][j4] = make_float4(h4[0], h4[1], h4[2], h4[3]);
        }
        __syncthreads();

        // ---------- Stage C: vertical conv + SSIM, 4 rows/thread ----------
        // 32 cols x 4 row-groups = 128 threads active (waves 0,1)
        if (tid < 128) {
            int j  = tid & 31;
            int i0 = (tid >> 5) * 4;
            float m1[4]  = {0,0,0,0}, m2[4]  = {0,0,0,0};
            float v11[4] = {0,0,0,0}, v22[4] = {0,0,0,0}, v12[4] = {0,0,0,0};
            #pragma unroll
            for (int t = 0; t < 14; ++t) {
                float b0 = hb[0][i0 + t][j];
                float b1 = hb[1][i0 + t][j];
                float b2 = hb[2][i0 + t][j];
                float b3 = hb[3][i0 + t][j];
                float b4 = hb[4][i0 + t][j];
                #pragma unroll
                for (int o = 0; o < 4; ++o) {
                    if (t - o >= 0 && t - o <= 10) {   // static after unroll
                        float g = gr[t - o];
                        m1[o]  += g * b0;
                        m2[o]  += g * b1;
                        v11[o] += g * b2;
                        v22[o] += g * b3;
                        v12[o] += g * b4;
                    }
                }
            }
            const float C1 = 0.0001f, C2 = 0.0009f;
            #pragma unroll
            for (int o = 0; o < 4; ++o) {
                int gy = y0 + i0 + o, gx = x0 + j;
                if (gy < H && gx < W) {
                    float mu1 = m1[o], mu2 = m2[o];
                    float mu11 = mu1 * mu1, mu22 = mu2 * mu2, mu12 = mu1 * mu2;
                    float s11 = v11[o] - mu11;
                    float s22 = v22[o] - mu22;
                    float s12 = v12[o] - mu12;
                    float num = (2.0f * mu12 + C1) * (2.0f * s12 + C2);
                    float den = (mu11 + mu22 + C1) * (s11 + s22 + C2);
                    acc += num / den;
                }
            }
        }
    }

    // ---------- block reduction ----------
    #pragma unroll
    for (int off = 32; off > 0; off >>= 1)
        acc += __shfl_down(acc, off, 64);
    int lane = tid & 63, wid = tid >> 6;
    if (lane == 0) wsum[wid] = acc;
    __syncthreads();
    if (tid == 0) {
        float total = wsum[0] + wsum[1] + wsum[2] + wsum[3];
        if (use_partials)
            ws[blockIdx.y * gridDim.x + blockIdx.x] = total;
        else
            atomicAdd(ws, total);
    }
}

extern "C" void kernel_launch(void* const* d_in, const int* in_sizes, int n_in,
                              void* d_out, int out_size, void* d_ws, size_t ws_size,
                              hipStream_t stream) {
    const float* img1   = (const float*)d_in[0];
    const float* img2   = (const float*)d_in[1];
    const float* window = (const float*)d_in[2];
    float* out = (float*)d_out;
    float* ws  = (float*)d_ws;

    long hw = (long)in_sizes[0] / 3;
    int W = (int)(sqrt((double)hw) + 0.5);
    int H = (int)(hw / W);

    float inv_n = (float)(1.0 / ((double)H * (double)W * 3.0));

    dim3 grid((W + TILE_W - 1) / TILE_W, (H + TILE_H - 1) / TILE_H);
    int nblocks = grid.x * grid.y;
    int use_partials = (ws_size >= (size_t)nblocks * sizeof(float)) ? 1 : 0;

    if (use_partials) {
        // 2-dispatch path: each block writes its own slot (no zeroing needed)
        ssim_kernel<<<grid, 256, 0, stream>>>(img1, img2, window, ws, H, W, 1);
        reduce_kernel<<<1, 1024, 0, stream>>>(ws, out, nblocks, inv_n);
    } else {
        // fallback: zero + atomic + finalize
        zero_kernel<<<1, 1, 0, stream>>>(ws);
        ssim_kernel<<<grid, 256, 0, stream>>>(img1, img2, window, ws, H, W, 0);
        finalize_kernel<<<1, 1, 0, stream>>>(ws, out, inv_n);
    }
}

// Round 3
// 226.216 us; speedup vs baseline: 1.5868x; 1.5868x over previous
//
#include <hip/hip_runtime.h>
#include <math.h>

#define TILE_W 32
#define TILE_H 16
#define HALO 5
#define IH   26      // TILE_H + 2*HALO
#define LDSW 44      // padded input-tile row stride (float4-aligned)
#define HBW  36      // padded hb row stride (32 -> 36 floats, float4-aligned)

__global__ void zero_kernel(float* ws) { ws[0] = 0.0f; }

__global__ void finalize_kernel(const float* ws, float* out, float inv_n) {
    out[0] = 1.0f - ws[0] * inv_n;
}

// Reduce per-block partials -> final loss. One block, 1024 threads.
__global__ void reduce_kernel(const float* __restrict__ ws, float* __restrict__ out,
                              int n, float inv_n) {
    __shared__ float s[16];
    float a = 0.0f;
    for (int i = threadIdx.x; i < n; i += 1024) a += ws[i];
    #pragma unroll
    for (int off = 32; off > 0; off >>= 1) a += __shfl_down(a, off, 64);
    if ((threadIdx.x & 63) == 0) s[threadIdx.x >> 6] = a;
    __syncthreads();
    if (threadIdx.x == 0) {
        float t = 0.0f;
        #pragma unroll
        for (int w = 0; w < 16; ++w) t += s[w];
        out[0] = 1.0f - t * inv_n;
    }
}

// block = 256 threads, tile = 32x16 output pixels, ONE channel per block
// (grid.z = 3). LDS = 27.9 KB. __launch_bounds__(256,4): 128-VGPR budget —
// R2's (256,5) forced VGPR=48 + 227 MB scratch spill; bound 4 fits Stage B's
// ~95 live floats with zero spill. Occupancy: min(LDS 5, VGPR 4) = 4 blk/CU.
__global__ __launch_bounds__(256, 4) void ssim_kernel(
    const float* __restrict__ img1, const float* __restrict__ img2,
    const float* __restrict__ window, float* __restrict__ ws,
    int H, int W, int use_partials)
{
    __shared__ float sx[IH][LDSW];
    __shared__ float sy[IH][LDSW];
    __shared__ float hb[5][IH][HBW];
    __shared__ float wsum[4];

    const int tid = threadIdx.x;
    const int x0  = blockIdx.x * TILE_W;
    const int y0  = blockIdx.y * TILE_H;
    const int c   = blockIdx.z;

    // Recover separable 1D Gaussian: g[j] = w2d[5][j] / sqrt(w2d[5][5])
    float gr[11];
    {
        float inv = 1.0f / sqrtf(window[60]);
        #pragma unroll
        for (int t = 0; t < 11; ++t) gr[t] = window[55 + t] * inv;
    }

    // interior: every load of this block is in-bounds
    const bool interior = (x0 >= HALO) && (x0 + 39 <= W) &&
                          (y0 >= HALO) && (y0 + 21 <= H);

    float acc = 0.0f;

    // ---------- Stage A: stage input tile (26 rows x 44 cols) ----------
    if (interior) {
        for (int item = tid; item < IH * 11; item += 256) {
            int r   = item / 11;
            int j4  = (item % 11) * 4;
            long base = ((long)(y0 + r - HALO) * W + (x0 + j4 - HALO)) * 3 + c;
            float vx[4], vy[4];
            #pragma unroll
            for (int k = 0; k < 4; ++k) {
                vx[k] = img1[base + 3 * k];
                vy[k] = img2[base + 3 * k];
            }
            *(float4*)&sx[r][j4] = make_float4(vx[0], vx[1], vx[2], vx[3]);
            *(float4*)&sy[r][j4] = make_float4(vy[0], vy[1], vy[2], vy[3]);
        }
    } else {
        for (int item = tid; item < IH * 11; item += 256) {
            int r   = item / 11;
            int j4  = (item % 11) * 4;
            int gh  = y0 + r - HALO;
            int gx0 = x0 + j4 - HALO;
            bool rowok = ((unsigned)gh < (unsigned)H);
            float vx[4], vy[4];
            #pragma unroll
            for (int k = 0; k < 4; ++k) {
                int gx = gx0 + k;
                bool ok = rowok && ((unsigned)gx < (unsigned)W);
                long off = ((long)gh * W + gx) * 3 + c;
                vx[k] = ok ? img1[off] : 0.0f;
                vy[k] = ok ? img2[off] : 0.0f;
            }
            *(float4*)&sx[r][j4] = make_float4(vx[0], vx[1], vx[2], vx[3]);
            *(float4*)&sy[r][j4] = make_float4(vy[0], vy[1], vy[2], vy[3]);
        }
    }
    __syncthreads();

    // ---------- Stage B: horizontal conv (5 quantities), 4 cols/thread ----
    // 26 rows x 8 col-groups = 208 items, single pass
    if (tid < IH * 8) {
        int r  = tid >> 3;
        int j4 = (tid & 7) * 4;
        float xv[16], yv[16];
        *(float4*)&xv[0]  = *(const float4*)&sx[r][j4];
        *(float4*)&xv[4]  = *(const float4*)&sx[r][j4 + 4];
        *(float4*)&xv[8]  = *(const float4*)&sx[r][j4 + 8];
        *(float4*)&xv[12] = *(const float4*)&sx[r][j4 + 12];
        *(float4*)&yv[0]  = *(const float4*)&sy[r][j4];
        *(float4*)&yv[4]  = *(const float4*)&sy[r][j4 + 4];
        *(float4*)&yv[8]  = *(const float4*)&sy[r][j4 + 8];
        *(float4*)&yv[12] = *(const float4*)&sy[r][j4 + 12];

        float h0[4] = {0,0,0,0}, h1[4] = {0,0,0,0}, h2[4] = {0,0,0,0};
        float h3[4] = {0,0,0,0}, h4[4] = {0,0,0,0};
        #pragma unroll
        for (int t = 0; t < 14; ++t) {
            float xs = xv[t] * xv[t];
            float ys = yv[t] * yv[t];
            float xy = xv[t] * yv[t];
            #pragma unroll
            for (int jj = 0; jj < 4; ++jj) {
                int k = t - jj;
                if (k >= 0 && k <= 10) {       // static after unroll
                    float g = gr[k];
                    h0[jj] += g * xv[t];
                    h1[jj] += g * yv[t];
                    h2[jj] += g * xs;
                    h3[jj] += g * ys;
                    h4[jj] += g * xy;
                }
            }
        }
        *(float4*)&hb[0][r][j4] = make_float4(h0[0], h0[1], h0[2], h0[3]);
        *(float4*)&hb[1][r][j4] = make_float4(h1[0], h1[1], h1[2], h1[3]);
        *(float4*)&hb[2][r][j4] = make_float4(h2[0], h2[1], h2[2], h2[3]);
        *(float4*)&hb[3][r][j4] = make_float4(h3[0], h3[1], h3[2], h3[3]);
        *(float4*)&hb[4][r][j4] = make_float4(h4[0], h4[1], h4[2], h4[3]);
    }
    __syncthreads();

    // ---------- Stage C: vertical conv + SSIM, 2 rows/thread ----------
    // 32 cols x 8 row-groups x 2 rows = all 256 threads active
    {
        int j  = tid & 31;
        int i0 = (tid >> 5) * 2;
        float m1[2]  = {0,0}, m2[2]  = {0,0};
        float v11[2] = {0,0}, v22[2] = {0,0}, v12[2] = {0,0};
        #pragma unroll
        for (int t = 0; t < 12; ++t) {
            float b0 = hb[0][i0 + t][j];
            float b1 = hb[1][i0 + t][j];
            float b2 = hb[2][i0 + t][j];
            float b3 = hb[3][i0 + t][j];
            float b4 = hb[4][i0 + t][j];
            #pragma unroll
            for (int o = 0; o < 2; ++o) {
                int k = t - o;
                if (k >= 0 && k <= 10) {       // static after unroll
                    float g = gr[k];
                    m1[o]  += g * b0;
                    m2[o]  += g * b1;
                    v11[o] += g * b2;
                    v22[o] += g * b3;
                    v12[o] += g * b4;
                }
            }
        }
        const float C1 = 0.0001f, C2 = 0.0009f;
        #pragma unroll
        for (int o = 0; o < 2; ++o) {
            int gy = y0 + i0 + o, gx = x0 + j;
            if (gy < H && gx < W) {
                float mu1 = m1[o], mu2 = m2[o];
                float mu11 = mu1 * mu1, mu22 = mu2 * mu2, mu12 = mu1 * mu2;
                float s11 = v11[o] - mu11;
                float s22 = v22[o] - mu22;
                float s12 = v12[o] - mu12;
                float num = (2.0f * mu12 + C1) * (2.0f * s12 + C2);
                float den = (mu11 + mu22 + C1) * (s11 + s22 + C2);
                acc += num / den;
            }
        }
    }

    // ---------- block reduction ----------
    #pragma unroll
    for (int off = 32; off > 0; off >>= 1)
        acc += __shfl_down(acc, off, 64);
    int lane = tid & 63, wid = tid >> 6;
    if (lane == 0) wsum[wid] = acc;
    __syncthreads();
    if (tid == 0) {
        float total = wsum[0] + wsum[1] + wsum[2] + wsum[3];
        if (use_partials)
            ws[(blockIdx.z * gridDim.y + blockIdx.y) * gridDim.x + blockIdx.x] = total;
        else
            atomicAdd(ws, total);
    }
}

extern "C" void kernel_launch(void* const* d_in, const int* in_sizes, int n_in,
                              void* d_out, int out_size, void* d_ws, size_t ws_size,
                              hipStream_t stream) {
    const float* img1   = (const float*)d_in[0];
    const float* img2   = (const float*)d_in[1];
    const float* window = (const float*)d_in[2];
    float* out = (float*)d_out;
    float* ws  = (float*)d_ws;

    long hw = (long)in_sizes[0] / 3;
    int W = (int)(sqrt((double)hw) + 0.5);
    int H = (int)(hw / W);

    float inv_n = (float)(1.0 / ((double)H * (double)W * 3.0));

    dim3 grid((W + TILE_W - 1) / TILE_W, (H + TILE_H - 1) / TILE_H, 3);
    long nblocks = (long)grid.x * grid.y * grid.z;
    int use_partials = (ws_size >= (size_t)nblocks * sizeof(float)) ? 1 : 0;

    if (use_partials) {
        ssim_kernel<<<grid, 256, 0, stream>>>(img1, img2, window, ws, H, W, 1);
        reduce_kernel<<<1, 1024, 0, stream>>>(ws, out, (int)nblocks, inv_n);
    } else {
        zero_kernel<<<1, 1, 0, stream>>>(ws);
        ssim_kernel<<<grid, 256, 0, stream>>>(img1, img2, window, ws, H, W, 0);
        finalize_kernel<<<1, 1, 0, stream>>>(ws, out, inv_n);
    }
}